// Round 1
// 1619.472 us; speedup vs baseline: 1.7343x; 1.7343x over previous
//
#include <hip/hip_runtime.h>
#include <hip/hip_bf16.h>

#define VOCAB  96
#define EMBED  32
#define HIDDEN 128
#define BATCH  512
#define TLEN   2048
#define KW     (EMBED + HIDDEN)   // 160
#define MROWS  (BATCH * TLEN)     // 1,048,576

typedef __attribute__((ext_vector_type(8))) short short8;    // 8 x bf16 bits
typedef __attribute__((ext_vector_type(4))) float float4v;

static __device__ __forceinline__ unsigned short f2bf_bits(float f) {
    __hip_bfloat16 b = __float2bfloat16(f);
    return *(unsigned short*)&b;
}

// ---------------------------------------------------------------------------
// Kernel A: Pe[v][i] = b_cell[i] + sum_k emb[v,k] * We[i,k]   (96 x 128)
// ---------------------------------------------------------------------------
__global__ void pe_precompute(const float* __restrict__ emb,
                              const float* __restrict__ W_cell,
                              const float* __restrict__ b_cell,
                              float* __restrict__ Pe) {
    const int tid = blockIdx.x * blockDim.x + threadIdx.x;
    if (tid >= VOCAB * HIDDEN) return;
    const int v = tid >> 7;
    const int i = tid & (HIDDEN - 1);
    float acc = b_cell[i];
    const float* e = emb + v * EMBED;
    const float* w = W_cell + i * KW;
    #pragma unroll
    for (int k = 0; k < EMBED; ++k) acc = fmaf(e[k], w[k], acc);
    Pe[tid] = acc;
}

// ---------------------------------------------------------------------------
// Kernel A2: W_dec fp32 -> bf16 bits (96 x 128)
// ---------------------------------------------------------------------------
__global__ void wdec_convert(const float* __restrict__ W_dec,
                             unsigned short* __restrict__ Wd) {
    const int tid = blockIdx.x * blockDim.x + threadIdx.x;
    if (tid < VOCAB * HIDDEN) Wd[tid] = f2bf_bits(W_dec[tid]);
}

// ---------------------------------------------------------------------------
// Kernel B: recurrence. One block = one batch row, 128 threads (2 waves).
// Thread i owns h[i]. h broadcast via v_readlane (VALU pipe), NOT per-lane
// full-h LDS reads. Cross-wave half exchanged through a 1 KB double buffer.
// Raw s_barrier + lgkmcnt(0): the per-step bf16 stash store is never drained
// inside the loop (no vmcnt(0) barrier stall).
// ---------------------------------------------------------------------------
__global__ __launch_bounds__(HIDDEN, 1)
void rnn_recur(const int* __restrict__ x,
               const float* __restrict__ h0,
               const float* __restrict__ W_cell,
               const float* __restrict__ Pe,
               float* __restrict__ out) {
    __shared__ float pe_lds[VOCAB * HIDDEN];           // 48 KB
    __shared__ int   x_lds[TLEN];                      // 8 KB
    __shared__ __align__(16) float hx_lds[2][HIDDEN];  // 1 KB h exchange

    const int i    = threadIdx.x;        // output index 0..127
    const int lane = i & 63;
    const int wid  = i >> 6;             // 0 or 1
    const int row  = blockIdx.x;

    // Wh row split: wo = own-wave half (k = wid*64+l), wx = other half.
    // Constant indexing after unroll -> stays in 128 VGPRs (no scratch).
    float wo[64], wx[64];
    {
        const float* src = W_cell + i * KW + EMBED;
        const float* so  = src + wid * 64;
        const float* sx  = src + (wid ^ 1) * 64;
        #pragma unroll
        for (int k = 0; k < 16; ++k) {
            const float4 a = *(const float4*)(so + 4 * k);
            wo[4*k+0] = a.x; wo[4*k+1] = a.y; wo[4*k+2] = a.z; wo[4*k+3] = a.w;
            const float4 b = *(const float4*)(sx + 4 * k);
            wx[4*k+0] = b.x; wx[4*k+1] = b.y; wx[4*k+2] = b.z; wx[4*k+3] = b.w;
        }
    }

    for (int n = i; n < VOCAB * HIDDEN; n += HIDDEN) pe_lds[n] = Pe[n];
    for (int n = i; n < TLEN; n += HIDDEN)           x_lds[n]  = x[row * TLEN + n];
    float hn = h0[row * HIDDEN + i];
    hx_lds[0][i] = hn;
    __syncthreads();

    const size_t rowbase = (size_t)row * TLEN;
    float* outp = out + rowbase * VOCAB;

    for (int t = 0; t < TLEN; ++t) {
        const int cur = t & 1;
        const int tok = x_lds[t];                          // wave-uniform
        const float pe = pe_lds[tok * HIDDEN + i];         // consumed at end
        const float ho = hx_lds[cur][(wid ^ 1) * 64 + lane]; // other-half elem

        const int hsb = __float_as_int(hn);
        float a0 = 0.f, a1 = 0.f, a2 = 0.f, a3 = 0.f;
        // own-wave half first (register broadcast, hides the ho LDS latency)
        #pragma unroll
        for (int l = 0; l < 64; l += 4) {
            a0 = fmaf(wo[l+0], __int_as_float(__builtin_amdgcn_readlane(hsb, l+0)), a0);
            a1 = fmaf(wo[l+1], __int_as_float(__builtin_amdgcn_readlane(hsb, l+1)), a1);
            a2 = fmaf(wo[l+2], __int_as_float(__builtin_amdgcn_readlane(hsb, l+2)), a2);
            a3 = fmaf(wo[l+3], __int_as_float(__builtin_amdgcn_readlane(hsb, l+3)), a3);
        }
        const int hob = __float_as_int(ho);
        #pragma unroll
        for (int l = 0; l < 64; l += 4) {
            a0 = fmaf(wx[l+0], __int_as_float(__builtin_amdgcn_readlane(hob, l+0)), a0);
            a1 = fmaf(wx[l+1], __int_as_float(__builtin_amdgcn_readlane(hob, l+1)), a1);
            a2 = fmaf(wx[l+2], __int_as_float(__builtin_amdgcn_readlane(hob, l+2)), a2);
            a3 = fmaf(wx[l+3], __int_as_float(__builtin_amdgcn_readlane(hob, l+3)), a3);
        }
        const float acc = ((a0 + a1) + (a2 + a3)) + pe;

        // tanh = 1 - 2/(exp(2x)+1)
        const float xa = fminf(fmaxf(acc, -12.f), 12.f);
        const float e2 = __expf(2.f * xa);
        hn = 1.f - 2.f / (e2 + 1.f);

        hx_lds[cur ^ 1][i] = hn;
        // fire-and-forget bf16 stash (drained only at kernel end)
        ((unsigned short*)outp)[i] = f2bf_bits(hn);
        outp += VOCAB;

        // LDS write visible, barrier — WITHOUT the vmcnt(0) store drain
        asm volatile("s_waitcnt lgkmcnt(0)" ::: "memory");
        __builtin_amdgcn_s_barrier();
        asm volatile("" ::: "memory");   // no loads hoisted above the barrier
    }

    out[(size_t)MROWS * VOCAB + row * HIDDEN + i] = hn;
}

// ---------------------------------------------------------------------------
// Kernel C: decode GEMM, bf16 MFMA 16x16x32, operands SWAPPED so that
// M = vocab, N = batch rows. D layout (col=lane&15 -> batch row,
// row=quad*4+reg -> vocab) gives 4 consecutive vocab per lane -> float4
// stores (6 dwordx4 per lane instead of 24 scattered dwords).
// A-frag: Wd[vt*16 + (lane&15)][k=quad*8+j]; B-frag: stash row (lane&15).
// ---------------------------------------------------------------------------
__global__ __launch_bounds__(256)
void decode_mfma(const unsigned short* __restrict__ Wd,
                 const float* __restrict__ b_dec,
                 float* __restrict__ out) {
    const int wave = threadIdx.x >> 6;
    const int lane = threadIdx.x & 63;
    const int l16  = lane & 15;
    const int quad = lane >> 4;
    const int rowbase = (blockIdx.x * 4 + wave) * 16;

    // B fragments: bf16 h-stash of row (rowbase + l16), 4 k-tiles
    const unsigned short* stash =
        (const unsigned short*)(out + (size_t)(rowbase + l16) * VOCAB);
    short8 b[4];
    #pragma unroll
    for (int kt = 0; kt < 4; ++kt)
        b[kt] = *(const short8*)(stash + kt * 32 + quad * 8);

    const size_t obase = (size_t)(rowbase + l16) * VOCAB + quad * 4;

    #pragma unroll
    for (int vt = 0; vt < 6; ++vt) {
        const unsigned short* wrow = Wd + (vt * 16 + l16) * HIDDEN + quad * 8;
        float4v acc = {0.f, 0.f, 0.f, 0.f};
        #pragma unroll
        for (int kt = 0; kt < 4; ++kt) {
            const short8 a = *(const short8*)(wrow + kt * 32);
            acc = __builtin_amdgcn_mfma_f32_16x16x32_bf16(a, b[kt], acc, 0, 0, 0);
        }
        const float4 bias = *(const float4*)(b_dec + vt * 16 + quad * 4);
        float4 res;
        res.x = acc[0] + bias.x;
        res.y = acc[1] + bias.y;
        res.z = acc[2] + bias.z;
        res.w = acc[3] + bias.w;
        *(float4*)(out + obase + vt * 16) = res;
    }
}

extern "C" void kernel_launch(void* const* d_in, const int* in_sizes, int n_in,
                              void* d_out, int out_size, void* d_ws, size_t ws_size,
                              hipStream_t stream) {
    const int*   x      = (const int*)  d_in[0];
    const float* h0     = (const float*)d_in[1];
    const float* emb    = (const float*)d_in[2];
    const float* W_cell = (const float*)d_in[3];
    const float* b_cell = (const float*)d_in[4];
    const float* W_dec  = (const float*)d_in[5];
    const float* b_dec  = (const float*)d_in[6];
    float* out = (float*)d_out;

    float*          Pe = (float*)d_ws;                          // 48 KB
    unsigned short* Wd = (unsigned short*)((char*)d_ws + VOCAB * HIDDEN * sizeof(float)); // 24 KB

    pe_precompute<<<(VOCAB * HIDDEN + 127) / 128, 128, 0, stream>>>(emb, W_cell, b_cell, Pe);
    wdec_convert<<<(VOCAB * HIDDEN + 255) / 256, 256, 0, stream>>>(W_dec, Wd);
    rnn_recur<<<BATCH, HIDDEN, 0, stream>>>(x, h0, W_cell, Pe, out);
    decode_mfma<<<MROWS / 64, 256, 0, stream>>>(Wd, b_dec, out);
}